// Round 4
// baseline (15777.768 us; speedup 1.0000x reference)
//
#include <hip/hip_runtime.h>

// LSTM: T=2048, B=32, E=512, H=512, fp32 in/out.
// R4 = R3 (data-as-flag, proven correct) with the retry storm fixed:
//   - SELECTIVE retry: first pass loads all 32 u64 h-chunks/lane and records a
//     miss bitmask; retry rounds re-load ONLY missing chunks (R3 re-loaded all
//     16KB/wave/round -> ~12MB/step chip-wide L3 poll storm -> 10.7ms).
//   - in-register publish pack: u64 h-chunk and float4 seq-store assembled via
//     __shfl_xor (lanes ej=0..3 adjacent) -> no LDS pbuf round-trip.
// Carried from R3 (harness-verified): 3-rotating h buffers, bf16-NaN sentinel
// 0x7FC0 (unreachable from tanh*sigmoid), re-arm of buf[(t+2)%3] right after
// poll success, vmcnt(0) fence enforcing re-arm-ack before data-store issue,
// hoisted emb-MFMA before the poll, wave-local wbuf transpose, ZERO in-loop
// barriers/flags. Topology: 128 WGs x 128 thr (R2 proved concentration is 3x
// worse; spread the per-step traffic).
// Race proof sketch (R3): consumer at step t+2 polls buf[s]; it got there only
// via h_{t+1}, whose store was issued after SENT(s) was ACK'd (vmcnt fence), so
// it can see SENT or fresh h_{t+2} — never stale h_{t-1}.

#define T_STEPS 2048
#define BATCH   32
#define EDIM    512
#define HDIM    512
#define NW      128   // recurrent workgroups
#define NJ      4     // h-columns per WG
#define NCOL    16    // packed gate columns per WG (4 gates * NJ)
#define WG_THREADS 128
#define BSTRIDE 1032  // 1024 + 8 pad (16B-aligned rows, kills LDS bank conflicts)
#define HQ      (BATCH * HDIM / 4)            // u64 chunks per h buffer (4096)

typedef unsigned int       u32;
typedef unsigned long long u64;
typedef unsigned short     u16;
typedef float  floatx4 __attribute__((ext_vector_type(4)));
typedef __bf16 bf16x8  __attribute__((ext_vector_type(8)));

#define SENT64 0x7FC07FC07FC07FC0ULL          // 4x bf16 NaN

union BF16U { __bf16 b; u16 u; };

__device__ __forceinline__ u16 f2bf(float f) { BF16U x; x.b = (__bf16)f; return x.u; }

__device__ __forceinline__ float fast_sigmoid(float x) {
  return 1.0f / (1.0f + __expf(-x));
}
__device__ __forceinline__ float fast_tanh(float x) {
  float e = __expf(-2.0f * fabsf(x));       // e in (0,1], no overflow
  float t = (1.0f - e) / (1.0f + e);
  return x >= 0.0f ? t : -t;
}

// ---------------------------------------------------------------- phase 1
// embb: fp32 -> bf16. hbuf[0] = bf16(h_0); hbuf[1], hbuf[2] = SENTINEL.
__global__ void lstm_prep(const float* __restrict__ emb, u16* __restrict__ embb,
                          const float* __restrict__ h0, u16* __restrict__ hb) {
  const size_t n4 = (size_t)T_STEPS * BATCH * EDIM / 4;
  size_t stride = (size_t)gridDim.x * blockDim.x;
  size_t gid = (size_t)blockIdx.x * blockDim.x + threadIdx.x;
  for (size_t i = gid; i < n4; i += stride) {
    float4 v = ((const float4*)emb)[i];
    ushort4 o;
    o.x = f2bf(v.x); o.y = f2bf(v.y); o.z = f2bf(v.z); o.w = f2bf(v.w);
    ((ushort4*)embb)[i] = o;
  }
  if (gid < (size_t)BATCH * HDIM) hb[gid] = f2bf(h0[gid]);
  u64* hq = (u64*)(hb + (size_t)BATCH * HDIM);   // buffers 1 and 2
  if (gid < 2 * HQ) hq[gid] = SENT64;
}

// ---------------------------------------------------------------- phase 2
__global__ void __launch_bounds__(WG_THREADS)
lstm_rec(const u16* __restrict__ embb,
         const float* __restrict__ c0,
         const float* __restrict__ Wx0, const float* __restrict__ Wh0, const float* __restrict__ b0,
         const float* __restrict__ Wx1, const float* __restrict__ Wh1, const float* __restrict__ b1,
         const float* __restrict__ Wx2, const float* __restrict__ Wh2, const float* __restrict__ b2,
         const float* __restrict__ Wx3, const float* __restrict__ Wh3, const float* __restrict__ b3,
         u16* __restrict__ hbuf,            // [3][BATCH*HDIM] bf16 (rotating)
         float* __restrict__ out) {
  __shared__ __align__(16) __bf16 Blds[NCOL][BSTRIDE];  // [packed col][k=E|H]
  __shared__ __align__(16) float wbuf[2][NCOL][20];     // gate transpose (per wave)

  const int tid    = threadIdx.x;
  const int w      = blockIdx.x;
  const int j0     = w * NJ;            // first h-column owned by this WG
  const int lane   = tid & 63;
  const int waveid = tid >> 6;          // 0..1 = M-tile (batch half)
  const int nlo    = lane & 15;
  const int q      = lane >> 4;
  const int mrow   = waveid * 16 + nlo; // batch row this lane loads A for

  const float* Wx[4] = {Wx0, Wx1, Wx2, Wx3};
  const float* Wh[4] = {Wh0, Wh1, Wh2, Wh3};

  // ---- stage weight slice into LDS as bf16: Blds[g*4+c][k] =
  //      k<512 ? Wx_g[k][j0+c] : Wh_g[k-512][j0+c]
  for (int g = 0; g < 4; ++g) {
    for (int base = 0; base < EDIM; base += WG_THREADS) {
      int kk = base + tid;
      float4 wx = *(const float4*)(Wx[g] + (size_t)kk * HDIM + j0);
      float4 wh = *(const float4*)(Wh[g] + (size_t)kk * HDIM + j0);
      Blds[g*NJ+0][kk] = (__bf16)wx.x;  Blds[g*NJ+0][EDIM+kk] = (__bf16)wh.x;
      Blds[g*NJ+1][kk] = (__bf16)wx.y;  Blds[g*NJ+1][EDIM+kk] = (__bf16)wh.y;
      Blds[g*NJ+2][kk] = (__bf16)wx.z;  Blds[g*NJ+2][EDIM+kk] = (__bf16)wh.z;
      Blds[g*NJ+3][kk] = (__bf16)wx.w;  Blds[g*NJ+3][EDIM+kk] = (__bf16)wh.w;
    }
  }

  // ---- per-lane epilogue state: lane owns (batch row er, h column jg).
  // C layout: col = nlo, row-in-Mtile = q*4 + reg.
  const int r0 = nlo >> 2;
  const int ej = nlo & 3;
  const int er = waveid * 16 + q * 4 + r0;   // batch row
  const int jg = j0 + ej;                    // global h column
  float cst = c0[(size_t)er * HDIM + jg];
  const float bgv = b0[jg], biv = b1[jg], bfv = b2[jg], bov = b3[jg];

  // publisher lanes: ej==0 lanes (16/wave) store one u64 (4 bf16 cols) of row er
  const bool publane = (ej == 0);
  const size_t puboff = (size_t)er * (HDIM / 4) + w;   // u64 index in h buffer

  __syncthreads();   // Blds ready (only barrier in the kernel)

  u64* const hq = (u64*)hbuf;

  for (int t = 0; t < T_STEPS; ++t) {
    // ---- x-part first: gates(pre) += emb_t @ Wx slice. No h_t dependence, so
    // its HBM latency overlaps other waves finishing step t-1.
    floatx4 acc0 = {0.f, 0.f, 0.f, 0.f};
    floatx4 acc1 = {0.f, 0.f, 0.f, 0.f};
    const u16* erow = embb + ((size_t)t * BATCH + mrow) * EDIM;
#pragma unroll
    for (int s = 0; s < 16; s += 2) {
      int k0 = s * 32 + q * 8;
      int k1 = (s + 1) * 32 + q * 8;
      bf16x8 a0 = *reinterpret_cast<const bf16x8*>(erow + k0);
      bf16x8 a1 = *reinterpret_cast<const bf16x8*>(erow + k1);
      bf16x8 w0 = *reinterpret_cast<const bf16x8*>(&Blds[nlo][k0]);
      bf16x8 w1 = *reinterpret_cast<const bf16x8*>(&Blds[nlo][k1]);
      acc0 = __builtin_amdgcn_mfma_f32_16x16x32_bf16(a0, w0, acc0, 0, 0, 0);
      acc1 = __builtin_amdgcn_mfma_f32_16x16x32_bf16(a1, w1, acc1, 0, 0, 0);
    }

    const u64* hc = hq + (size_t)(t % 3) * HQ;             // consume h_t
    u64*       hn = hq + (size_t)((t + 1) % 3) * HQ;       // produce h_{t+1}
    u64*       hs = hq + (size_t)((t + 2) % 3) * HQ;       // re-arm for t+1

    // ---- data-as-flag poll with SELECTIVE retry: first pass loads all 32
    // chunks and builds a miss mask; retries touch only missing chunks
    // (usually 1-2 u64 from the one straggler WG).
    const u64* hrow = hc + (size_t)mrow * (HDIM / 4);
    u64 hreg[32];
    u32 miss = 0u;
#pragma unroll
    for (int i2 = 0; i2 < 16; ++i2) {
      int base = i2 * 8 + q * 2;
      hreg[2*i2]   = __hip_atomic_load(&hrow[base],   __ATOMIC_RELAXED, __HIP_MEMORY_SCOPE_AGENT);
      hreg[2*i2+1] = __hip_atomic_load(&hrow[base+1], __ATOMIC_RELAXED, __HIP_MEMORY_SCOPE_AGENT);
      if (hreg[2*i2]   == SENT64) miss |= (1u << (2*i2));
      if (hreg[2*i2+1] == SENT64) miss |= (1u << (2*i2+1));
    }
    while (__any(miss != 0u)) {
#pragma unroll
      for (int i = 0; i < 32; ++i) {
        if (miss & (1u << i)) {
          int base = (i >> 1) * 8 + q * 2 + (i & 1);
          hreg[i] = __hip_atomic_load(&hrow[base], __ATOMIC_RELAXED, __HIP_MEMORY_SCOPE_AGENT);
          if (hreg[i] != SENT64) miss &= ~(1u << i);
        }
      }
    }

    // ---- re-arm sentinel for the buffer written at t+1 (holds dead h_{t-1}).
    // Issued early; its ACK is enforced by the vmcnt(0) fence below.
    if (publane)
      __hip_atomic_store(&hs[puboff], SENT64, __ATOMIC_RELAXED, __HIP_MEMORY_SCOPE_AGENT);

    // ---- h part MFMA from registers
#pragma unroll
    for (int s = 0; s < 16; s += 2) {
      int k0 = s * 32 + q * 8;
      int k1 = (s + 1) * 32 + q * 8;
      union { u64 qv[2]; bf16x8 v; } ua, ub;
      ua.qv[0] = hreg[2*s];     ua.qv[1] = hreg[2*s+1];
      ub.qv[0] = hreg[2*s+2];   ub.qv[1] = hreg[2*s+3];
      bf16x8 w0 = *reinterpret_cast<const bf16x8*>(&Blds[nlo][EDIM + k0]);
      bf16x8 w1 = *reinterpret_cast<const bf16x8*>(&Blds[nlo][EDIM + k1]);
      acc0 = __builtin_amdgcn_mfma_f32_16x16x32_bf16(ua.v, w0, acc0, 0, 0, 0);
      acc1 = __builtin_amdgcn_mfma_f32_16x16x32_bf16(ub.v, w1, acc1, 0, 0, 0);
    }

    // ---- wave-local transpose (same-wave DS ordering, no barrier)
    floatx4 sum;
#pragma unroll
    for (int r = 0; r < 4; ++r) sum[r] = acc0[r] + acc1[r];
    *reinterpret_cast<floatx4*>(&wbuf[waveid][nlo][q * 4]) = sum;

    float pg = wbuf[waveid][ej     ][q * 4 + r0];
    float pi = wbuf[waveid][ej +  4][q * 4 + r0];
    float pf = wbuf[waveid][ej +  8][q * 4 + r0];
    float po = wbuf[waveid][ej + 12][q * 4 + r0];

    float gv = fast_tanh   (pg + bgv);
    float iv = fast_sigmoid(pi + biv);
    float fv = fast_sigmoid(pf + bfv);
    float ov = fast_sigmoid(po + bov);
    cst = gv * iv + cst * fv;
    float hv = fast_tanh(cst) * ov;

    // ---- in-register pack: lanes ej=0..3 are consecutive; two shfl_xor steps
    // assemble the u64 bf16 chunk and the float4 seq vector in lane ej=0.
    u32 b16  = (u32)f2bf(hv);
    u32 lo32 = b16 | (((u32)__shfl_xor((int)b16, 1)) << 16);   // [ej0,ej1]
    u32 hi32 = (u32)__shfl_xor((int)lo32, 2);                  // [ej2,ej3]
    u64 pk   = (u64)lo32 | ((u64)hi32 << 32);
    float f1 = __shfl_xor(hv, 1);
    float f2 = __shfl_xor(hv, 2);
    float f3 = __shfl_xor(f1, 2);

    // vmcnt(0): guarantees the SENT re-arm (issued pre-MFMA) has COMPLETED
    // before the data store is issued — the rotation's soundness condition.
    asm volatile("s_waitcnt vmcnt(0)" ::: "memory");
    if (publane) {
      __hip_atomic_store(&hn[puboff], pk, __ATOMIC_RELAXED, __HIP_MEMORY_SCOPE_AGENT);
      // off-critical-path: seq output as one coalesced 16B store
      float4 hv4 = {hv, f1, f2, f3};
      *reinterpret_cast<float4*>(out + ((size_t)t * BATCH + er) * HDIM + j0) = hv4;
      if (t == T_STEPS - 1) {
        const size_t seqN = (size_t)T_STEPS * BATCH * HDIM;
        *reinterpret_cast<float4*>(out + seqN + (size_t)er * HDIM + j0) = hv4;  // h_T
      }
    }
    if (t == T_STEPS - 1) {
      const size_t seqN = (size_t)T_STEPS * BATCH * HDIM;
      out[seqN + (size_t)BATCH * HDIM + (size_t)er * HDIM + jg] = cst;          // c_T
    }
  }
}

// ---------------------------------------------------------------- launch
extern "C" void kernel_launch(void* const* d_in, const int* in_sizes, int n_in,
                              void* d_out, int out_size, void* d_ws, size_t ws_size,
                              hipStream_t stream) {
  const float* emb = (const float*)d_in[0];
  const float* h0  = (const float*)d_in[1];
  const float* c0  = (const float*)d_in[2];
  const float* Wgx = (const float*)d_in[3];
  const float* Wgh = (const float*)d_in[4];
  const float* bg  = (const float*)d_in[5];
  const float* Wix = (const float*)d_in[6];
  const float* Wih = (const float*)d_in[7];
  const float* bi  = (const float*)d_in[8];
  const float* Wfx = (const float*)d_in[9];
  const float* Wfh = (const float*)d_in[10];
  const float* bf  = (const float*)d_in[11];
  const float* Wox = (const float*)d_in[12];
  const float* Woh = (const float*)d_in[13];
  const float* bo  = (const float*)d_in[14];
  float* out = (float*)d_out;

  char* ws = (char*)d_ws;
  const size_t embb_bytes = (size_t)T_STEPS * BATCH * EDIM * 2;   // 67,108,864
  u16* embb  = (u16*)ws;
  u16* hbuf  = (u16*)(ws + embb_bytes);                           // 3*32768 B

  lstm_prep<<<4096, 256, 0, stream>>>(emb, embb, h0, hbuf);
  lstm_rec<<<NW, WG_THREADS, 0, stream>>>(embb, c0,
                                          Wgx, Wgh, bg,
                                          Wix, Wih, bi,
                                          Wfx, Wfh, bf,
                                          Wox, Woh, bo,
                                          hbuf, out);
}

// Round 5
// 8803.557 us; speedup vs baseline: 1.7922x; 1.7922x over previous
//
#include <hip/hip_runtime.h>

// LSTM: T=2048, B=32, E=512, H=512, fp32 in/out.
// R5 = R1 skeleton (flags + tiny probe; best measured, 7.29ms) with three
// serial-path cuts. R3/R4 lesson: data-as-flag loses either way (re-stream
// payload = bandwidth storm, selective = serialized round-trips) — poll must
// be a minimal probe, payload fetched once after success.
//   (1) emb software pipeline: ereg[16] prefetched one step ahead; emb-MFMA is
//       pure-register -> ~900cy HBM latency off the ring's serial path.
//   (2) per-WAVE flags, two independent rings: batch M-tiles are independent
//       recurrences (wave w reads only rows it produces). flags[waveid][128];
//       each wave drains its own h-store (vmcnt(0)) then stores its own flag.
//       ZERO in-loop barriers; straggler pool halves (128 per ring).
//   (3) in-register publish pack via shfl (R4-proven): 16 u64 stores/wave;
//       seq float4 stores strictly after flag store (off critical path).

#define T_STEPS 2048
#define BATCH   32
#define EDIM    512
#define HDIM    512
#define NW      128   // recurrent workgroups
#define NJ      4     // h-columns per WG
#define NCOL    16    // packed gate columns per WG (4 gates * NJ)
#define WG_THREADS 128
#define BSTRIDE 1032  // 1024 + 8 pad (16B-aligned rows, kills LDS bank conflicts)

typedef unsigned int       u32;
typedef unsigned long long u64;
typedef unsigned short     u16;
typedef float  floatx4 __attribute__((ext_vector_type(4)));
typedef __bf16 bf16x8  __attribute__((ext_vector_type(8)));

union BF16U { __bf16 b; u16 u; };

__device__ __forceinline__ u16 f2bf(float f) { BF16U x; x.b = (__bf16)f; return x.u; }

__device__ __forceinline__ float fast_sigmoid(float x) {
  return 1.0f / (1.0f + __expf(-x));
}
__device__ __forceinline__ float fast_tanh(float x) {
  float e = __expf(-2.0f * fabsf(x));       // e in (0,1], no overflow
  float t = (1.0f - e) / (1.0f + e);
  return x >= 0.0f ? t : -t;
}

// ---------------------------------------------------------------- phase 1
__global__ void lstm_prep(const float* __restrict__ emb, u16* __restrict__ embb,
                          const float* __restrict__ h0, u16* __restrict__ hb,
                          u32* __restrict__ flags) {
  const size_t n4 = (size_t)T_STEPS * BATCH * EDIM / 4;
  size_t stride = (size_t)gridDim.x * blockDim.x;
  size_t gid = (size_t)blockIdx.x * blockDim.x + threadIdx.x;
  for (size_t i = gid; i < n4; i += stride) {
    float4 v = ((const float4*)emb)[i];
    ushort4 o;
    o.x = f2bf(v.x); o.y = f2bf(v.y); o.z = f2bf(v.z); o.w = f2bf(v.w);
    ((ushort4*)embb)[i] = o;
  }
  if (gid < (size_t)BATCH * HDIM) hb[gid] = f2bf(h0[gid]);
  if (gid < 2 * NW) flags[gid] = 0u;   // flags[2][128]
}

// ---------------------------------------------------------------- phase 2
__global__ void __launch_bounds__(WG_THREADS)
lstm_rec(const u16* __restrict__ embb,
         const float* __restrict__ c0,
         const float* __restrict__ Wx0, const float* __restrict__ Wh0, const float* __restrict__ b0,
         const float* __restrict__ Wx1, const float* __restrict__ Wh1, const float* __restrict__ b1,
         const float* __restrict__ Wx2, const float* __restrict__ Wh2, const float* __restrict__ b2,
         const float* __restrict__ Wx3, const float* __restrict__ Wh3, const float* __restrict__ b3,
         u16* __restrict__ hbuf,            // [2][BATCH*HDIM] bf16
         u32* __restrict__ flags,           // [2][NW] per-wave, per-ring
         float* __restrict__ out) {
  __shared__ __align__(16) __bf16 Blds[NCOL][BSTRIDE];  // [packed col][k=E|H]
  __shared__ __align__(16) float wbuf[2][NCOL][20];     // gate transpose (per wave)

  const int tid    = threadIdx.x;
  const int w      = blockIdx.x;
  const int j0     = w * NJ;            // first h-column owned by this WG
  const int lane   = tid & 63;
  const int waveid = tid >> 6;          // 0..1 = M-tile (batch half) = ring id
  const int nlo    = lane & 15;
  const int q      = lane >> 4;
  const int mrow   = waveid * 16 + nlo; // batch row this lane loads A for

  const float* Wx[4] = {Wx0, Wx1, Wx2, Wx3};
  const float* Wh[4] = {Wh0, Wh1, Wh2, Wh3};

  // ---- stage weight slice into LDS as bf16: Blds[g*4+c][k] =
  //      k<512 ? Wx_g[k][j0+c] : Wh_g[k-512][j0+c]
  for (int g = 0; g < 4; ++g) {
    for (int base = 0; base < EDIM; base += WG_THREADS) {
      int kk = base + tid;
      float4 wx = *(const float4*)(Wx[g] + (size_t)kk * HDIM + j0);
      float4 wh = *(const float4*)(Wh[g] + (size_t)kk * HDIM + j0);
      Blds[g*NJ+0][kk] = (__bf16)wx.x;  Blds[g*NJ+0][EDIM+kk] = (__bf16)wh.x;
      Blds[g*NJ+1][kk] = (__bf16)wx.y;  Blds[g*NJ+1][EDIM+kk] = (__bf16)wh.y;
      Blds[g*NJ+2][kk] = (__bf16)wx.z;  Blds[g*NJ+2][EDIM+kk] = (__bf16)wh.z;
      Blds[g*NJ+3][kk] = (__bf16)wx.w;  Blds[g*NJ+3][EDIM+kk] = (__bf16)wh.w;
    }
  }

  // ---- per-lane epilogue state: lane owns (batch row er, h column jg).
  // C layout: col = nlo, row-in-Mtile = q*4 + reg.
  const int r0 = nlo >> 2;
  const int ej = nlo & 3;
  const int er = waveid * 16 + q * 4 + r0;   // batch row
  const int jg = j0 + ej;                    // global h column
  float cst = c0[(size_t)er * HDIM + jg];
  const float bgv = b0[jg], biv = b1[jg], bfv = b2[jg], bov = b3[jg];

  // publisher lanes: ej==0 lanes (16/wave) store one u64 (4 bf16 cols) of row er
  const bool publane = (ej == 0);
  const size_t puboff = (size_t)er * (HDIM / 4) + w;   // u64 index in h buffer

  __syncthreads();   // Blds ready (only barrier in the kernel)

  // per-ring flag array: this wave polls ONLY its own ring's 128 flags
  const u64* f8 = (const u64*)(flags + waveid * NW);   // 64 lanes x u64 = 128
  u32* const myflag = flags + waveid * NW + w;

  // ---- prologue: prefetch emb registers for t=0
  bf16x8 ereg[16];
  {
    const u16* erow = embb + (size_t)mrow * EDIM;
#pragma unroll
    for (int s = 0; s < 16; ++s)
      ereg[s] = *reinterpret_cast<const bf16x8*>(erow + s * 32 + q * 8);
  }

  for (int t = 0; t < T_STEPS; ++t) {
    // ---- emb-MFMA from prefetched registers (pure compute, no memory wait)
    floatx4 acc0 = {0.f, 0.f, 0.f, 0.f};
    floatx4 acc1 = {0.f, 0.f, 0.f, 0.f};
#pragma unroll
    for (int s = 0; s < 16; s += 2) {
      int k0 = s * 32 + q * 8;
      int k1 = (s + 1) * 32 + q * 8;
      bf16x8 w0 = *reinterpret_cast<const bf16x8*>(&Blds[nlo][k0]);
      bf16x8 w1 = *reinterpret_cast<const bf16x8*>(&Blds[nlo][k1]);
      acc0 = __builtin_amdgcn_mfma_f32_16x16x32_bf16(ereg[s],     w0, acc0, 0, 0, 0);
      acc1 = __builtin_amdgcn_mfma_f32_16x16x32_bf16(ereg[s + 1], w1, acc1, 0, 0, 0);
    }

    // ---- prefetch emb for t+1 (drains during poll + h-MFMA + epilogue)
    if (t + 1 < T_STEPS) {
      const u16* erow = embb + ((size_t)(t + 1) * BATCH + mrow) * EDIM;
#pragma unroll
      for (int s = 0; s < 16; ++s)
        ereg[s] = *reinterpret_cast<const bf16x8*>(erow + s * 32 + q * 8);
    }

    // ---- poll own ring: one u64 atomic load per lane (2 flags), tight spin
    for (;;) {
      u64 v = __hip_atomic_load(&f8[lane], __ATOMIC_RELAXED, __HIP_MEMORY_SCOPE_AGENT);
      int ok = ((u32)v >= (u32)t) && ((u32)(v >> 32) >= (u32)t);
      if (__all(ok)) break;
    }

    const u16* hcur  = hbuf + (size_t)(t & 1) * (BATCH * HDIM);
    u64*       hnext = (u64*)(hbuf + (size_t)((t + 1) & 1) * (BATCH * HDIM));

    // ---- h part: one pipelined payload fetch (guaranteed present), MFMA
    const u64* hrow = (const u64*)(hcur + (size_t)mrow * HDIM);
#pragma unroll
    for (int s = 0; s < 16; s += 2) {
      int k0 = s * 32 + q * 8;
      int k1 = (s + 1) * 32 + q * 8;
      union { u64 qv[2]; bf16x8 v; } ua, ub;
      ua.qv[0] = __hip_atomic_load(&hrow[(k0 >> 2) + 0], __ATOMIC_RELAXED, __HIP_MEMORY_SCOPE_AGENT);
      ua.qv[1] = __hip_atomic_load(&hrow[(k0 >> 2) + 1], __ATOMIC_RELAXED, __HIP_MEMORY_SCOPE_AGENT);
      ub.qv[0] = __hip_atomic_load(&hrow[(k1 >> 2) + 0], __ATOMIC_RELAXED, __HIP_MEMORY_SCOPE_AGENT);
      ub.qv[1] = __hip_atomic_load(&hrow[(k1 >> 2) + 1], __ATOMIC_RELAXED, __HIP_MEMORY_SCOPE_AGENT);
      bf16x8 w0 = *reinterpret_cast<const bf16x8*>(&Blds[nlo][EDIM + k0]);
      bf16x8 w1 = *reinterpret_cast<const bf16x8*>(&Blds[nlo][EDIM + k1]);
      acc0 = __builtin_amdgcn_mfma_f32_16x16x32_bf16(ua.v, w0, acc0, 0, 0, 0);
      acc1 = __builtin_amdgcn_mfma_f32_16x16x32_bf16(ub.v, w1, acc1, 0, 0, 0);
    }

    // ---- wave-local transpose (same-wave DS ordering, no barrier)
    floatx4 sum;
#pragma unroll
    for (int r = 0; r < 4; ++r) sum[r] = acc0[r] + acc1[r];
    *reinterpret_cast<floatx4*>(&wbuf[waveid][nlo][q * 4]) = sum;

    float pg = wbuf[waveid][ej     ][q * 4 + r0];
    float pi = wbuf[waveid][ej +  4][q * 4 + r0];
    float pf = wbuf[waveid][ej +  8][q * 4 + r0];
    float po = wbuf[waveid][ej + 12][q * 4 + r0];

    float gv = fast_tanh   (pg + bgv);
    float iv = fast_sigmoid(pi + biv);
    float fv = fast_sigmoid(pf + bfv);
    float ov = fast_sigmoid(po + bov);
    cst = gv * iv + cst * fv;
    float hv = fast_tanh(cst) * ov;

    // ---- in-register pack: lanes ej=0..3 adjacent; 2 shfl_xor -> u64 chunk
    u32 b16  = (u32)f2bf(hv);
    u32 lo32 = b16 | (((u32)__shfl_xor((int)b16, 1)) << 16);   // [ej0,ej1]
    u32 hi32 = (u32)__shfl_xor((int)lo32, 2);                  // [ej2,ej3]
    u64 pk   = (u64)lo32 | ((u64)hi32 << 32);

    // ---- publish: h store -> vmcnt(0) (h acked agent-wide) -> own flag.
    // The fence also retires the t+1 emb prefetch (in-order vmcnt) — those
    // loads have had poll+MFMA+epilogue (~2us) to complete.
    if (publane)
      __hip_atomic_store(&hnext[puboff], pk, __ATOMIC_RELAXED, __HIP_MEMORY_SCOPE_AGENT);
    asm volatile("s_waitcnt vmcnt(0)" ::: "memory");
    if (lane == 0)
      __hip_atomic_store(myflag, (u32)(t + 1), __ATOMIC_RELAXED, __HIP_MEMORY_SCOPE_AGENT);

    // ---- off-critical-path outputs (drain at next step's fence)
    float f1 = __shfl_xor(hv, 1);
    float f2 = __shfl_xor(hv, 2);
    float f3 = __shfl_xor(f1, 2);
    if (publane) {
      float4 hv4 = {hv, f1, f2, f3};
      *reinterpret_cast<float4*>(out + ((size_t)t * BATCH + er) * HDIM + j0) = hv4;
      if (t == T_STEPS - 1) {
        const size_t seqN = (size_t)T_STEPS * BATCH * HDIM;
        *reinterpret_cast<float4*>(out + seqN + (size_t)er * HDIM + j0) = hv4;  // h_T
      }
    }
    if (t == T_STEPS - 1) {
      const size_t seqN = (size_t)T_STEPS * BATCH * HDIM;
      out[seqN + (size_t)BATCH * HDIM + (size_t)er * HDIM + jg] = cst;          // c_T
    }
  }
}

// ---------------------------------------------------------------- launch
extern "C" void kernel_launch(void* const* d_in, const int* in_sizes, int n_in,
                              void* d_out, int out_size, void* d_ws, size_t ws_size,
                              hipStream_t stream) {
  const float* emb = (const float*)d_in[0];
  const float* h0  = (const float*)d_in[1];
  const float* c0  = (const float*)d_in[2];
  const float* Wgx = (const float*)d_in[3];
  const float* Wgh = (const float*)d_in[4];
  const float* bg  = (const float*)d_in[5];
  const float* Wix = (const float*)d_in[6];
  const float* Wih = (const float*)d_in[7];
  const float* bi  = (const float*)d_in[8];
  const float* Wfx = (const float*)d_in[9];
  const float* Wfh = (const float*)d_in[10];
  const float* bf  = (const float*)d_in[11];
  const float* Wox = (const float*)d_in[12];
  const float* Woh = (const float*)d_in[13];
  const float* bo  = (const float*)d_in[14];
  float* out = (float*)d_out;

  char* ws = (char*)d_ws;
  const size_t embb_bytes = (size_t)T_STEPS * BATCH * EDIM * 2;   // 67,108,864
  u16* embb  = (u16*)ws;
  u16* hbuf  = (u16*)(ws + embb_bytes);                           // 2*32768 B
  u32* flags = (u32*)(ws + embb_bytes + 2 * (size_t)BATCH * HDIM * 2);

  lstm_prep<<<4096, 256, 0, stream>>>(emb, embb, h0, hbuf, flags);
  lstm_rec<<<NW, WG_THREADS, 0, stream>>>(embb, c0,
                                          Wgx, Wgh, bg,
                                          Wix, Wih, bi,
                                          Wfx, Wfh, bf,
                                          Wox, Woh, bo,
                                          hbuf, flags, out);
}